// Round 6
// baseline (264.496 us; speedup 1.0000x reference)
//
#include <hip/hip_runtime.h>
#include <float.h>

#define NP 8192
#define CAP 64           // survivor slots per query (expected ~11-25)
typedef unsigned long long u64;

// fused kernel geometry: 8 queries/wave, 4 waves/block, 256 blocks/pass
#define FQ 8
#define FW 4
#define FB 256
#define FQB (FW * FQ)    // 32
#define FBLK (NP / FQB)  // 256
// cross kernel geometry: 4 queries/wave -> 512 blocks (2 blocks/CU)
#define CQ 4
#define CW 4
#define CB 256
#define CQB (CW * CQ)    // 16
#define CBLK (NP / CQB)  // 512

// ws float offsets
#define O_PC1  0         // float4[NP]: pc1  (x,y,z,|p|^2)
#define O_PC2  (4 * NP)  // float4[NP]: pc2
#define O_WARP (8 * NP)  // float4[NP]: warp
#define O_FLOW (12 * NP) // float4[NP]: flow (w unused)
#define O_C2C  (16 * NP) // SoA x,y,z: c2curv
#define O_MC   (19 * NP) // SoA x,y,z: mcurv
#define O_ACC  (22 * NP) // acc[0]=chamfer acc[1]=smooth acc[2]=curv

__device__ __forceinline__ float wavemin_f(float v) {
#pragma unroll
  for (int s = 1; s < 64; s <<= 1) v = fminf(v, __shfl_xor(v, s, 64));
  return v;
}

// score = |p|^2 - 2 p.q (nq = -2q); true sqdist = score + |q|^2.
// Same FMA sequence everywhere so threshold compares are bitwise-consistent.
__device__ __forceinline__ float score1(float4 c, float nx, float ny, float nz) {
  return fmaf(c.x, nx, fmaf(c.y, ny, fmaf(c.z, nz, c.w)));
}

// smallest remaining (s,j) across the wave; first-lane pick on exact ties.
__device__ __forceinline__ void extract1f(float& s, int& j, int lane,
                                          float& od, int& oj) {
  float w = wavemin_f(s);
  u64 msk = __ballot(s == w);
  int src = (int)__ffsll(msk) - 1;
  oj = __shfl(j, src, 64);
  if (lane == src) s = FLT_MAX;
  od = w;
}

// Two-scan exact top-K filter, candidates streamed from global (L2-resident).
// scan1: branchless per-lane min. T[q] = K-th smallest of the 64 lane minima
//   (value knockout) — the K knocked-out lanes own K distinct candidates <= T,
//   so the global K-th smallest <= T.
// scan2: every score <= T[q] appended to the wave's LDS survivor list.
template<int K, int Q>
__device__ __forceinline__ void wave_filter(const float4* __restrict__ cand,
                                            const float (&nqx)[Q],
                                            const float (&nqy)[Q],
                                            const float (&nqz)[Q],
                                            float (*hs)[CAP], int (*hj)[CAP],
                                            int* scnt, float (&T)[Q]) {
  const int lane = threadIdx.x & 63;
  float m[Q];
#pragma unroll
  for (int q = 0; q < Q; ++q) m[q] = FLT_MAX;

  // ---- scan 1: per-lane minima (lane's disjoint 1/64 slice) ----
#pragma unroll 4
  for (int j = lane; j < NP; j += 64) {
    float4 c = cand[j];
#pragma unroll
    for (int q = 0; q < Q; ++q) m[q] = fminf(m[q], score1(c, nqx[q], nqy[q], nqz[q]));
  }

  // ---- threshold: K-th smallest lane-min via value knockout ----
#pragma unroll
  for (int q = 0; q < Q; ++q) {
    float mm = m[q], t = 0.f;
#pragma unroll
    for (int r = 0; r < K; ++r) {
      float w = wavemin_f(mm);
      u64 msk = __ballot(mm == w);
      if (lane == (int)__ffsll(msk) - 1) mm = FLT_MAX;
      t = w;
    }
    T[q] = t;
  }

  // ---- init survivor buffers (wave-private; in-wave LDS order suffices) ----
#pragma unroll
  for (int q = 0; q < Q; ++q) {
    hs[q][lane] = FLT_MAX;
    hj[q][lane] = 0;
    if (lane == 0) scnt[q] = 0;
  }

  // ---- scan 2: collect all score <= T[q] ----
#pragma unroll 2
  for (int j = lane; j < NP; j += 64) {
    float4 c = cand[j];
    float s[Q];
    bool any = false;
#pragma unroll
    for (int q = 0; q < Q; ++q) {
      s[q] = score1(c, nqx[q], nqy[q], nqz[q]);
      any |= (s[q] <= T[q]);
    }
    if (any) {
#pragma unroll
      for (int q = 0; q < Q; ++q) {
        if (s[q] <= T[q]) {
          int p = atomicAdd(scnt + q, 1);
          if (p < CAP) { hs[q][p] = s[q]; hj[q][p] = j; }
        }
      }
    }
  }
  __syncthreads();  // drain LDS writes before extraction reads
}

__global__ void k_prep(const float* __restrict__ pred, const float* __restrict__ gt,
                       const float* __restrict__ coords, float* __restrict__ ws) {
  int i = blockIdx.x * blockDim.x + threadIdx.x;
  if (i < NP) {
    float cx = coords[3 * i], cy = coords[3 * i + 1], cz = coords[3 * i + 2];
    float gx = gt[3 * i],     gy = gt[3 * i + 1],     gz = gt[3 * i + 2];
    float px = pred[3 * i],   py = pred[3 * i + 1],   pz = pred[3 * i + 2];
    float ax = cx + gx, ay = cy + gy, az = cz + gz;   // pc2
    float bx = cx + px, by = cy + py, bz = cz + pz;   // warp
    float4* pc1q  = (float4*)(ws + O_PC1);
    float4* pc2q  = (float4*)(ws + O_PC2);
    float4* warpq = (float4*)(ws + O_WARP);
    float4* flowq = (float4*)(ws + O_FLOW);
    pc1q[i]  = make_float4(cx, cy, cz, cx * cx + cy * cy + cz * cz);
    pc2q[i]  = make_float4(ax, ay, az, ax * ax + ay * ay + az * az);
    warpq[i] = make_float4(bx, by, bz, bx * bx + by * by + bz * bz);
    flowq[i] = make_float4(px, py, pz, 0.f);
  }
  if (i < 4) ws[O_ACC + i] = 0.f;
}

// fused: pass0 = pc2 x pc2 top-10 -> c2curv
//        pass1 = pc1 x pc1 top-10 -> mcurv (warp gather) + smooth (flow)
//        pass2 = pc2 x warp  min  -> chamfer dist2
__global__ __launch_bounds__(FB) void k_fused(float* __restrict__ ws) {
  __shared__ float hs[FW][FQ][CAP];
  __shared__ int   hj[FW][FQ][CAP];
  __shared__ int   scnt[FW][FQ];
  __shared__ float red[FW];
  const int pass = blockIdx.x / FBLK;
  const int pb   = blockIdx.x % FBLK;
  const int wave = threadIdx.x >> 6, lane = threadIdx.x & 63;
  const int i0 = pb * FQB + wave * FQ;
  const float4* pc1q  = (const float4*)(ws + O_PC1);
  const float4* pc2q  = (const float4*)(ws + O_PC2);
  const float4* warpq = (const float4*)(ws + O_WARP);
  const float4* flowq = (const float4*)(ws + O_FLOW);

  if (pass == 0) {
    float qx[FQ], qy[FQ], qz[FQ], nqx[FQ], nqy[FQ], nqz[FQ], T[FQ];
#pragma unroll
    for (int q = 0; q < FQ; ++q) {
      float4 p = pc2q[i0 + q];
      qx[q] = p.x; qy[q] = p.y; qz[q] = p.z;
      nqx[q] = -2.f * p.x; nqy[q] = -2.f * p.y; nqz[q] = -2.f * p.z;
    }
    wave_filter<10, FQ>(pc2q, nqx, nqy, nqz, hs[wave], hj[wave], scnt[wave], T);
#pragma unroll
    for (int q = 0; q < FQ; ++q) {
      float s = hs[wave][q][lane]; int j = hj[wave][q][lane];
      float ax = 0.f, ay = 0.f, az = 0.f;
#pragma unroll
      for (int r = 0; r < 10; ++r) {
        float od; int oj;
        extract1f(s, j, lane, od, oj);
        float4 g = pc2q[oj];
        ax += g.x; ay += g.y; az += g.z;
      }
      if (lane == 0) {
        const float inv9 = 1.f / 9.f;
        const int i = i0 + q;
        ws[O_C2C + 0 * NP + i] = (ax - 10.f * qx[q]) * inv9;
        ws[O_C2C + 1 * NP + i] = (ay - 10.f * qy[q]) * inv9;
        ws[O_C2C + 2 * NP + i] = (az - 10.f * qz[q]) * inv9;
      }
    }
  } else if (pass == 1) {
    float nqx[FQ], nqy[FQ], nqz[FQ], T[FQ];
#pragma unroll
    for (int q = 0; q < FQ; ++q) {
      float4 p = pc1q[i0 + q];
      nqx[q] = -2.f * p.x; nqy[q] = -2.f * p.y; nqz[q] = -2.f * p.z;
    }
    wave_filter<10, FQ>(pc1q, nqx, nqy, nqz, hs[wave], hj[wave], scnt[wave], T);
    float smw = 0.f;
#pragma unroll
    for (int q = 0; q < FQ; ++q) {
      const int i = i0 + q;
      float4 wi = warpq[i];
      float4 fi = flowq[i];
      float s = hs[wave][q][lane]; int j = hj[wave][q][lane];
      float ax = 0.f, ay = 0.f, az = 0.f, sm = 0.f;
#pragma unroll
      for (int r = 0; r < 10; ++r) {
        float od; int oj;
        extract1f(s, j, lane, od, oj);
        float4 g = warpq[oj];
        ax += g.x; ay += g.y; az += g.z;
        if (r < 9) {
          float4 f = flowq[oj];
          float gx_ = f.x - fi.x, gy_ = f.y - fi.y, gz_ = f.z - fi.z;
          sm += sqrtf(gx_ * gx_ + gy_ * gy_ + gz_ * gz_);
        }
      }
      smw += sm * 0.125f;
      if (lane == 0) {
        const float inv9 = 1.f / 9.f;
        ws[O_MC + 0 * NP + i] = (ax - 10.f * wi.x) * inv9;
        ws[O_MC + 1 * NP + i] = (ay - 10.f * wi.y) * inv9;
        ws[O_MC + 2 * NP + i] = (az - 10.f * wi.z) * inv9;
      }
    }
    if (lane == 0) red[wave] = smw;
    __syncthreads();
    if (threadIdx.x == 0) {
      float s = 0.f;
#pragma unroll
      for (int t = 0; t < FW; ++t) s += red[t];
      atomicAdd(ws + O_ACC + 1, s);
    }
  } else {
    // reverse chamfer: pc2 queries over warp candidates, min only
    float nqx[FQ], nqy[FQ], nqz[FQ], qw[FQ], m[FQ];
#pragma unroll
    for (int q = 0; q < FQ; ++q) {
      float4 p = pc2q[i0 + q];
      nqx[q] = -2.f * p.x; nqy[q] = -2.f * p.y; nqz[q] = -2.f * p.z;
      qw[q] = p.w;
      m[q] = FLT_MAX;
    }
#pragma unroll 4
    for (int j = lane; j < NP; j += 64) {
      float4 c = warpq[j];
#pragma unroll
      for (int q = 0; q < FQ; ++q) m[q] = fminf(m[q], score1(c, nqx[q], nqy[q], nqz[q]));
    }
    float s = 0.f;
#pragma unroll
    for (int q = 0; q < FQ; ++q) s += wavemin_f(m[q]) + qw[q];
    if (lane == 0) red[wave] = s;
    __syncthreads();
    if (threadIdx.x == 0) {
      float t0 = 0.f;
#pragma unroll
      for (int t = 0; t < FW; ++t) t0 += red[t];
      atomicAdd(ws + O_ACC + 0, t0);
    }
  }
}

// warp x pc2 top-5 -> chamfer dist1 + interpolated-curvature loss
__global__ __launch_bounds__(CB) void k_cross(float* __restrict__ ws) {
  __shared__ float hs[CW][CQ][CAP];
  __shared__ int   hj[CW][CQ][CAP];
  __shared__ int   scnt[CW][CQ];
  __shared__ float redc[CW], redv[CW];
  const float4* pc2q  = (const float4*)(ws + O_PC2);
  const float4* warpq = (const float4*)(ws + O_WARP);
  const int wave = threadIdx.x >> 6, lane = threadIdx.x & 63;
  const int i0 = blockIdx.x * CQB + wave * CQ;
  float nqx[CQ], nqy[CQ], nqz[CQ], qw[CQ], T[CQ];
#pragma unroll
  for (int q = 0; q < CQ; ++q) {
    float4 p = warpq[i0 + q];
    nqx[q] = -2.f * p.x; nqy[q] = -2.f * p.y; nqz[q] = -2.f * p.z;
    qw[q] = p.w;
  }
  wave_filter<5, CQ>(pc2q, nqx, nqy, nqz, hs[wave], hj[wave], scnt[wave], T);
  float csum = 0.f, vsum = 0.f;
#pragma unroll
  for (int q = 0; q < CQ; ++q) {
    const int i = i0 + q;
    float s = hs[wave][q][lane]; int j = hj[wave][q][lane];
    float wsum = 0.f, ix = 0.f, iy = 0.f, iz = 0.f, d1 = 0.f;
#pragma unroll
    for (int r = 0; r < 5; ++r) {
      float od; int oj;
      extract1f(s, j, lane, od, oj);
      float d = od + qw[q];          // true squared distance
      if (r == 0) d1 = d;
      float wt = 1.f / (d + 1e-8f);
      wsum += wt;
      ix += wt * ws[O_C2C + 0 * NP + oj];
      iy += wt * ws[O_C2C + 1 * NP + oj];
      iz += wt * ws[O_C2C + 2 * NP + oj];
    }
    float inv = 1.f / wsum;
    float ex = ix * inv - ws[O_MC + 0 * NP + i];
    float ey = iy * inv - ws[O_MC + 1 * NP + i];
    float ez = iz * inv - ws[O_MC + 2 * NP + i];
    csum += d1;
    vsum += ex * ex + ey * ey + ez * ez;
  }
  if (lane == 0) { redc[wave] = csum; redv[wave] = vsum; }
  __syncthreads();
  if (threadIdx.x == 0) {
    float sc = 0.f, sv = 0.f;
#pragma unroll
    for (int t = 0; t < CW; ++t) { sc += redc[t]; sv += redv[t]; }
    atomicAdd(ws + O_ACC + 0, sc);
    atomicAdd(ws + O_ACC + 2, sv);
  }
}

__global__ void k_final(const float* __restrict__ ws, float* __restrict__ out) {
  float ch = ws[O_ACC + 0];
  float sm = ws[O_ACC + 1];
  float cv = ws[O_ACC + 2];
  out[0] = 0.02f * ch + 0.02f * 0.3f * cv + 0.02f * sm;
}

extern "C" void kernel_launch(void* const* d_in, const int* in_sizes, int n_in,
                              void* d_out, int out_size, void* d_ws, size_t ws_size,
                              hipStream_t stream) {
  (void)in_sizes; (void)n_in; (void)out_size; (void)ws_size;
  const float* pred   = (const float*)d_in[0];
  const float* gt     = (const float*)d_in[1];
  const float* coords = (const float*)d_in[2];
  float* ws  = (float*)d_ws;
  float* out = (float*)d_out;

  k_prep<<<dim3(NP / 256), dim3(256), 0, stream>>>(pred, gt, coords, ws);
  k_fused<<<dim3(3 * FBLK), dim3(FB), 0, stream>>>(ws);
  k_cross<<<dim3(CBLK), dim3(CB), 0, stream>>>(ws);
  k_final<<<1, 1, 0, stream>>>(ws, out);
}

// Round 7
// 184.212 us; speedup vs baseline: 1.4358x; 1.4358x over previous
//
#include <hip/hip_runtime.h>
#include <float.h>

#define NP 8192
#define CAP 64           // survivor slots per query (expected ~11-25)
#define NW 4             // waves per block
#define TB 256           // threads per block
#define CHUNK4 1024      // float4 candidates per staged chunk (16 KB)
#define FQ 8             // fused: queries/wave  -> 256 blocks/pass, 768 total
#define CQ 4             // cross: queries/wave  -> 512 blocks
typedef unsigned long long u64;

// ws float offsets
#define O_PC1  0          // float4[NP]: pc1  (x,y,z,|p|^2)
#define O_PC2  (4 * NP)   // float4[NP]: pc2
#define O_WARP (8 * NP)   // float4[NP]: warp
#define O_FLOW (12 * NP)  // float4[NP]: flow (w unused)
#define O_C2C  (16 * NP)  // SoA x,y,z: c2curv
#define O_MC   (19 * NP)  // SoA x,y,z: mcurv
#define O_ACC  (22 * NP)  // acc[0]=chamfer acc[1]=smooth acc[2]=curv

__device__ __forceinline__ float wavemin_f(float v) {
#pragma unroll
  for (int s = 1; s < 64; s <<= 1) v = fminf(v, __shfl_xor(v, s, 64));
  return v;
}

// score = |p|^2 - 2 p.q (nq = -2q); true sqdist = score + |q|^2.
// Same FMA sequence everywhere so threshold compares are bitwise-consistent.
__device__ __forceinline__ float score1(float4 c, float nx, float ny, float nz) {
  return fmaf(c.x, nx, fmaf(c.y, ny, fmaf(c.z, nz, c.w)));
}

// smallest remaining (s,j) across the wave; first-lane pick on exact ties.
__device__ __forceinline__ void extract1f(float& s, int& j, int lane,
                                          float& od, int& oj) {
  float w = wavemin_f(s);
  u64 msk = __ballot(s == w);
  int src = (int)__ffsll(msk) - 1;
  oj = __shfl(j, src, 64);
  if (lane == src) s = FLT_MAX;
  od = w;
}

// Stage-and-scan over all NP candidates with register-prefetch double buffer:
// issue chunk c+1 global loads into regs BEFORE computing chunk c from LDS
// (T14 issue-early/write-late) — global latency hides under chunk compute;
// LDS stays single-buffered. f(j, cand_j) is called for every candidate.
template<typename F>
__device__ __forceinline__ void scan_chunks(const float4* __restrict__ cand,
                                            float4* __restrict__ sbuf, F f) {
  const int t = threadIdx.x;
  const int lane = t & 63;
  float4 r0 = cand[t], r1 = cand[t + 256], r2 = cand[t + 512], r3 = cand[t + 768];
  for (int c = 0; c < NP; c += CHUNK4) {
    __syncthreads();                       // prior chunk's readers done
    sbuf[t] = r0; sbuf[t + 256] = r1; sbuf[t + 512] = r2; sbuf[t + 768] = r3;
    if (c + CHUNK4 < NP) {
      const float4* nx = cand + c + CHUNK4;
      r0 = nx[t]; r1 = nx[t + 256]; r2 = nx[t + 512]; r3 = nx[t + 768];
    }
    __syncthreads();                       // staged chunk visible
#pragma unroll 4
    for (int g = 0; g < CHUNK4; g += 64) f(c + g + lane, sbuf[g + lane]);
  }
}

// K-th smallest of the 64 lane-minima via value knockout. The K knocked-out
// lanes own K distinct candidates <= T, so the global K-th smallest <= T.
template<int K, int Q>
__device__ __forceinline__ void knockout(const float (&m)[Q], float (&T)[Q], int lane) {
#pragma unroll
  for (int q = 0; q < Q; ++q) {
    float mm = m[q], t = 0.f;
#pragma unroll
    for (int r = 0; r < K; ++r) {
      float w = wavemin_f(mm);
      u64 msk = __ballot(mm == w);
      if (lane == (int)__ffsll(msk) - 1) mm = FLT_MAX;
      t = w;
    }
    T[q] = t;
  }
}

__global__ void k_prep(const float* __restrict__ pred, const float* __restrict__ gt,
                       const float* __restrict__ coords, float* __restrict__ ws) {
  int i = blockIdx.x * blockDim.x + threadIdx.x;
  if (i < NP) {
    float cx = coords[3 * i], cy = coords[3 * i + 1], cz = coords[3 * i + 2];
    float gx = gt[3 * i],     gy = gt[3 * i + 1],     gz = gt[3 * i + 2];
    float px = pred[3 * i],   py = pred[3 * i + 1],   pz = pred[3 * i + 2];
    float ax = cx + gx, ay = cy + gy, az = cz + gz;   // pc2
    float bx = cx + px, by = cy + py, bz = cz + pz;   // warp
    ((float4*)(ws + O_PC1))[i]  = make_float4(cx, cy, cz, cx * cx + cy * cy + cz * cz);
    ((float4*)(ws + O_PC2))[i]  = make_float4(ax, ay, az, ax * ax + ay * ay + az * az);
    ((float4*)(ws + O_WARP))[i] = make_float4(bx, by, bz, bx * bx + by * by + bz * bz);
    ((float4*)(ws + O_FLOW))[i] = make_float4(px, py, pz, 0.f);
  }
  if (i < 4) ws[O_ACC + i] = 0.f;
}

// fused: pass0 = pc2 x pc2 top-10 -> c2curv
//        pass1 = pc1 x pc1 top-10 -> mcurv (warp gather) + smooth (flow)
//        pass2 = pc2 x warp  min  -> chamfer dist2
__global__ __launch_bounds__(TB, 3) void k_fused(float* __restrict__ ws) {
  __shared__ __align__(16) float4 sbuf[CHUNK4];
  __shared__ float hs[NW][FQ][CAP];
  __shared__ int   hj[NW][FQ][CAP];
  __shared__ int   scnt[NW][FQ];
  __shared__ float red[NW];
  const int pass = blockIdx.x % 3;
  const int pb   = blockIdx.x / 3;
  const int wave = threadIdx.x >> 6, lane = threadIdx.x & 63;
  const int i0 = pb * (NW * FQ) + wave * FQ;
  const float4* pc1q  = (const float4*)(ws + O_PC1);
  const float4* pc2q  = (const float4*)(ws + O_PC2);
  const float4* warpq = (const float4*)(ws + O_WARP);
  const float4* flowq = (const float4*)(ws + O_FLOW);

  if (pass == 2) {
    // reverse chamfer: pc2 queries over warp candidates, min only (1 scan)
    float nqx[FQ], nqy[FQ], nqz[FQ], qw[FQ], m[FQ];
#pragma unroll
    for (int q = 0; q < FQ; ++q) {
      float4 p = pc2q[i0 + q];
      nqx[q] = -2.f * p.x; nqy[q] = -2.f * p.y; nqz[q] = -2.f * p.z;
      qw[q] = p.w;
      m[q] = FLT_MAX;
    }
    scan_chunks(warpq, sbuf, [&](int j, float4 c) {
#pragma unroll
      for (int q = 0; q < FQ; ++q) m[q] = fminf(m[q], score1(c, nqx[q], nqy[q], nqz[q]));
    });
    float s = 0.f;
#pragma unroll
    for (int q = 0; q < FQ; ++q) s += wavemin_f(m[q]) + qw[q];
    if (lane == 0) red[wave] = s;
    __syncthreads();
    if (threadIdx.x == 0) {
      float t0 = 0.f;
#pragma unroll
      for (int t = 0; t < NW; ++t) t0 += red[t];
      atomicAdd(ws + O_ACC + 0, t0);
    }
    return;
  }

  const float4* cand = (pass == 0) ? pc2q : pc1q;
  float nqx[FQ], nqy[FQ], nqz[FQ], m[FQ], T[FQ];
#pragma unroll
  for (int q = 0; q < FQ; ++q) {
    float4 p = cand[i0 + q];
    nqx[q] = -2.f * p.x; nqy[q] = -2.f * p.y; nqz[q] = -2.f * p.z;
    m[q] = FLT_MAX;
  }
  // scan 1: branchless per-lane minima over the lane's disjoint 1/64 slice
  scan_chunks(cand, sbuf, [&](int j, float4 c) {
#pragma unroll
    for (int q = 0; q < FQ; ++q) m[q] = fminf(m[q], score1(c, nqx[q], nqy[q], nqz[q]));
  });
  knockout<10, FQ>(m, T, lane);
  // init survivor buffers (wave-private)
#pragma unroll
  for (int q = 0; q < FQ; ++q) {
    hs[wave][q][lane] = FLT_MAX;
    hj[wave][q][lane] = 0;
    if (lane == 0) scnt[wave][q] = 0;
  }
  // scan 2: collect all score <= T[q]
  scan_chunks(cand, sbuf, [&](int j, float4 c) {
    float s[FQ]; bool any = false;
#pragma unroll
    for (int q = 0; q < FQ; ++q) {
      s[q] = score1(c, nqx[q], nqy[q], nqz[q]);
      any |= (s[q] <= T[q]);
    }
    if (__ballot(any) != 0ULL) {
#pragma unroll
      for (int q = 0; q < FQ; ++q) {
        if (s[q] <= T[q]) {
          int p = atomicAdd(&scnt[wave][q], 1);
          if (p < CAP) { hs[wave][q][p] = s[q]; hj[wave][q][p] = j; }
        }
      }
    }
  });
  __syncthreads();  // drain survivor LDS writes

  if (pass == 0) {
#pragma unroll
    for (int q = 0; q < FQ; ++q) {
      float s = hs[wave][q][lane]; int j = hj[wave][q][lane];
      float ax = 0.f, ay = 0.f, az = 0.f;
#pragma unroll
      for (int r = 0; r < 10; ++r) {
        float od; int oj;
        extract1f(s, j, lane, od, oj);
        float4 g = pc2q[oj];
        ax += g.x; ay += g.y; az += g.z;
      }
      if (lane == 0) {
        const float inv9 = 1.f / 9.f;
        const int i = i0 + q;
        float qx = -0.5f * nqx[q], qy = -0.5f * nqy[q], qz = -0.5f * nqz[q];
        ws[O_C2C + 0 * NP + i] = (ax - 10.f * qx) * inv9;
        ws[O_C2C + 1 * NP + i] = (ay - 10.f * qy) * inv9;
        ws[O_C2C + 2 * NP + i] = (az - 10.f * qz) * inv9;
      }
    }
  } else {
    float smw = 0.f;
#pragma unroll
    for (int q = 0; q < FQ; ++q) {
      const int i = i0 + q;
      float4 wi = warpq[i];
      float4 fi = flowq[i];
      float s = hs[wave][q][lane]; int j = hj[wave][q][lane];
      float ax = 0.f, ay = 0.f, az = 0.f, sm = 0.f;
#pragma unroll
      for (int r = 0; r < 10; ++r) {
        float od; int oj;
        extract1f(s, j, lane, od, oj);
        float4 g = warpq[oj];
        ax += g.x; ay += g.y; az += g.z;
        if (r < 9) {
          float4 f = flowq[oj];
          float gx_ = f.x - fi.x, gy_ = f.y - fi.y, gz_ = f.z - fi.z;
          sm += sqrtf(gx_ * gx_ + gy_ * gy_ + gz_ * gz_);
        }
      }
      smw += sm * 0.125f;
      if (lane == 0) {
        const float inv9 = 1.f / 9.f;
        ws[O_MC + 0 * NP + i] = (ax - 10.f * wi.x) * inv9;
        ws[O_MC + 1 * NP + i] = (ay - 10.f * wi.y) * inv9;
        ws[O_MC + 2 * NP + i] = (az - 10.f * wi.z) * inv9;
      }
    }
    if (lane == 0) red[wave] = smw;
    __syncthreads();
    if (threadIdx.x == 0) {
      float s = 0.f;
#pragma unroll
      for (int t = 0; t < NW; ++t) s += red[t];
      atomicAdd(ws + O_ACC + 1, s);
    }
  }
}

// warp x pc2 top-5 -> chamfer dist1 + interpolated-curvature loss
__global__ __launch_bounds__(TB, 3) void k_cross(float* __restrict__ ws) {
  __shared__ __align__(16) float4 sbuf[CHUNK4];
  __shared__ float hs[NW][CQ][CAP];
  __shared__ int   hj[NW][CQ][CAP];
  __shared__ int   scnt[NW][CQ];
  __shared__ float redc[NW], redv[NW];
  const float4* pc2q  = (const float4*)(ws + O_PC2);
  const float4* warpq = (const float4*)(ws + O_WARP);
  const int wave = threadIdx.x >> 6, lane = threadIdx.x & 63;
  const int i0 = blockIdx.x * (NW * CQ) + wave * CQ;
  float nqx[CQ], nqy[CQ], nqz[CQ], qw[CQ], m[CQ], T[CQ];
#pragma unroll
  for (int q = 0; q < CQ; ++q) {
    float4 p = warpq[i0 + q];
    nqx[q] = -2.f * p.x; nqy[q] = -2.f * p.y; nqz[q] = -2.f * p.z;
    qw[q] = p.w;
    m[q] = FLT_MAX;
  }
  scan_chunks(pc2q, sbuf, [&](int j, float4 c) {
#pragma unroll
    for (int q = 0; q < CQ; ++q) m[q] = fminf(m[q], score1(c, nqx[q], nqy[q], nqz[q]));
  });
  knockout<5, CQ>(m, T, lane);
#pragma unroll
  for (int q = 0; q < CQ; ++q) {
    hs[wave][q][lane] = FLT_MAX;
    hj[wave][q][lane] = 0;
    if (lane == 0) scnt[wave][q] = 0;
  }
  scan_chunks(pc2q, sbuf, [&](int j, float4 c) {
    float s[CQ]; bool any = false;
#pragma unroll
    for (int q = 0; q < CQ; ++q) {
      s[q] = score1(c, nqx[q], nqy[q], nqz[q]);
      any |= (s[q] <= T[q]);
    }
    if (__ballot(any) != 0ULL) {
#pragma unroll
      for (int q = 0; q < CQ; ++q) {
        if (s[q] <= T[q]) {
          int p = atomicAdd(&scnt[wave][q], 1);
          if (p < CAP) { hs[wave][q][p] = s[q]; hj[wave][q][p] = j; }
        }
      }
    }
  });
  __syncthreads();
  float csum = 0.f, vsum = 0.f;
#pragma unroll
  for (int q = 0; q < CQ; ++q) {
    const int i = i0 + q;
    float s = hs[wave][q][lane]; int j = hj[wave][q][lane];
    float wsum = 0.f, ix = 0.f, iy = 0.f, iz = 0.f, d1 = 0.f;
#pragma unroll
    for (int r = 0; r < 5; ++r) {
      float od; int oj;
      extract1f(s, j, lane, od, oj);
      float d = od + qw[q];           // true squared distance
      if (r == 0) d1 = d;
      float wt = 1.f / (d + 1e-8f);
      wsum += wt;
      ix += wt * ws[O_C2C + 0 * NP + oj];
      iy += wt * ws[O_C2C + 1 * NP + oj];
      iz += wt * ws[O_C2C + 2 * NP + oj];
    }
    float inv = 1.f / wsum;
    float ex = ix * inv - ws[O_MC + 0 * NP + i];
    float ey = iy * inv - ws[O_MC + 1 * NP + i];
    float ez = iz * inv - ws[O_MC + 2 * NP + i];
    csum += d1;
    vsum += ex * ex + ey * ey + ez * ez;
  }
  if (lane == 0) { redc[wave] = csum; redv[wave] = vsum; }
  __syncthreads();
  if (threadIdx.x == 0) {
    float sc = 0.f, sv = 0.f;
#pragma unroll
    for (int t = 0; t < NW; ++t) { sc += redc[t]; sv += redv[t]; }
    atomicAdd(ws + O_ACC + 0, sc);
    atomicAdd(ws + O_ACC + 2, sv);
  }
}

__global__ void k_final(const float* __restrict__ ws, float* __restrict__ out) {
  float ch = ws[O_ACC + 0];
  float sm = ws[O_ACC + 1];
  float cv = ws[O_ACC + 2];
  out[0] = 0.02f * ch + 0.02f * 0.3f * cv + 0.02f * sm;
}

extern "C" void kernel_launch(void* const* d_in, const int* in_sizes, int n_in,
                              void* d_out, int out_size, void* d_ws, size_t ws_size,
                              hipStream_t stream) {
  (void)in_sizes; (void)n_in; (void)out_size; (void)ws_size;
  const float* pred   = (const float*)d_in[0];
  const float* gt     = (const float*)d_in[1];
  const float* coords = (const float*)d_in[2];
  float* ws  = (float*)d_ws;
  float* out = (float*)d_out;

  k_prep<<<dim3(NP / TB), dim3(TB), 0, stream>>>(pred, gt, coords, ws);
  k_fused<<<dim3(3 * (NP / (NW * FQ))), dim3(TB), 0, stream>>>(ws);
  k_cross<<<dim3(NP / (NW * CQ)), dim3(TB), 0, stream>>>(ws);
  k_final<<<1, 1, 0, stream>>>(ws, out);
}